// Round 20
// baseline (62.712 us; speedup 1.0000x reference)
//
#include <hip/hip_runtime.h>

typedef unsigned short ushort_t;
typedef __attribute__((ext_vector_type(8))) __bf16 bf16x8;
typedef __attribute__((ext_vector_type(4))) float f32x4;
typedef __attribute__((ext_vector_type(4))) unsigned int u32x4;
typedef __attribute__((ext_vector_type(8))) unsigned short u16x8;

#define NQ 8192
#define NK 8192
#define DD 256
#define NSPLIT 8
#define SEG (NK / NSPLIT)   // 1024 K-rows per split
#define KBLK 64             // K rows staged in LDS per tile (32 KB)
#define NT (SEG / KBLK)     // 16 tiles per block
#define LOG2E 1.4426950408889634f
#define LN2 0.6931471805599453f

using gptr_t = const __attribute__((address_space(1))) void*;
using lptr_t = __attribute__((address_space(3))) void*;

__device__ __forceinline__ float fexp2(float x) { return __builtin_amdgcn_exp2f(x); }
__device__ __forceinline__ float flog2(float x) { return __builtin_amdgcn_logf(x); }

// round-to-nearest-even fp32 -> bf16
__device__ __forceinline__ ushort_t f2bf(float f) {
  unsigned int u = __builtin_bit_cast(unsigned int, f);
  unsigned int r = 0x7FFFu + ((u >> 16) & 1u);
  return (ushort_t)((u + r) >> 16);
}

// ---------------------------------------------------------------------------
// Kernel 1: projections OUT_bf16[8192x256] = X_fp32 @ W, transpose FUSED
// (R15-proven).  grid (128, 2, 4).
// ---------------------------------------------------------------------------
__global__ __launch_bounds__(256) void proj_kernel(
    const float* __restrict__ xq, const float* __restrict__ xk,
    const float* __restrict__ Wq, const float* __restrict__ Wk,
    ushort_t* __restrict__ Qb, ushort_t* __restrict__ Kb) {
  __shared__ __align__(16) char wt_lds[64 * 512];  // 32 KB
  const float* X = (blockIdx.y == 0) ? xq : xk;
  const float* W = (blockIdx.y == 0) ? Wq : Wk;
  ushort_t* OUT = (blockIdx.y == 0) ? Qb : Kb;
  const float scale = (blockIdx.y == 0) ? LOG2E : 1.0f;

  const int tid = threadIdx.x;
  const int w = tid >> 6, lane = tid & 63;
  const int g = lane >> 4, c = lane & 15;
  const int rbase = blockIdx.x * 64 + w * 16;
  const int ctbase = blockIdx.z * 4;

  {
    const int n_ = tid & 63;
    const int kb = (tid >> 6) * 2;
    const int nglob = blockIdx.z * 64 + n_;
#pragma unroll
    for (int i = 0; i < 32; ++i) {
      int k = i * 8 + kb;
      float w0 = W[(size_t)k * 256 + nglob];
      float w1 = W[(size_t)(k + 1) * 256 + nglob];
      unsigned int pk = (unsigned int)f2bf(w0) | ((unsigned int)f2bf(w1) << 16);
      int ch = i ^ (n_ & 7);
      *reinterpret_cast<unsigned int*>(&wt_lds[n_ * 512 + ch * 16 + (k & 7) * 2]) = pk;
    }
  }

  bf16x8 a[8];
#pragma unroll
  for (int kk = 0; kk < 8; ++kk) {
    const f32x4* px =
        reinterpret_cast<const f32x4*>(X + (size_t)(rbase + c) * DD + kk * 32 + g * 8);
    f32x4 x0 = px[0], x1 = px[1];
    u16x8 v;
#pragma unroll
    for (int j = 0; j < 4; ++j) { v[j] = f2bf(x0[j]); v[4 + j] = f2bf(x1[j]); }
    a[kk] = __builtin_bit_cast(bf16x8, v);
  }
  __syncthreads();

#pragma unroll
  for (int ct0 = 0; ct0 < 4; ++ct0) {
    const int jrl = ct0 * 16 + c;
    f32x4 acc = {0.f, 0.f, 0.f, 0.f};
#pragma unroll
    for (int kk = 0; kk < 8; ++kk) {
      int ch = (kk * 4 + g) ^ (c & 7);
      bf16x8 b = *reinterpret_cast<const bf16x8*>(&wt_lds[jrl * 512 + ch * 16]);
      acc = __builtin_amdgcn_mfma_f32_16x16x32_bf16(a[kk], b, acc, 0, 0, 0);
    }
    int ct = ctbase + ct0;
#pragma unroll
    for (int r = 0; r < 4; ++r)
      OUT[(size_t)(rbase + g * 4 + r) * DD + ct * 16 + c] = f2bf(acc[r] * scale);
  }
}

// ---------------------------------------------------------------------------
// Kernel 2: flash-style scores + online base-2 logsumexp partials.
// R20: m201-style PHASE SCHEDULE (T3+T4+T5).  Each K-tile = 4 sub-phases by
// output quadrant jt: {ds_read 8 B-frags; issue 2 gload_lds (next tile);
// barrier; lgkmcnt(0); setprio(1); 16 MFMA; setprio(0); barrier}.  vmcnt is
// COUNTED (vmcnt(2) once per tile, after phase0's stage-issue) -- prefetch
// never drains in-loop.  Single acc set + fresh per-phase quad buffer keeps
// registers ~166 unified.  Race audit: phase0 vmcnt+barrier precedes all
// buf[cur] reads; STAGE2 targets buf[cur^1] whose readers finished at the
// prev tile's last lgkm(0)+barrier; barriers wave-uniform.
// Eight 2-phase variants pinned at 44+-1 us (no pipe >50%); the catalog's
// regime gate says this schedule is the prerequisite lever (+28-41% GEMM).
// ---------------------------------------------------------------------------
__global__ __launch_bounds__(256, 2) void scores_lse_kernel(
    const ushort_t* __restrict__ Qb, const ushort_t* __restrict__ Kb,
    float* __restrict__ pm, float* __restrict__ ps) {
  __shared__ __align__(128) char smem[2][KBLK * 512];  // 64 KB
  const int tid = threadIdx.x;
  const int w = tid >> 6, lane = tid & 63;
  const int g = lane >> 4, c = lane & 15;
  const int qw = blockIdx.x * 128 + w * 32;
  const int j0 = blockIdx.y * SEG;

  // A-frags: 2 row-tiles x 8 k-steps (64 VGPRs, resident whole kernel).
  bf16x8 a[2][8];
#pragma unroll
  for (int rt = 0; rt < 2; ++rt)
#pragma unroll
    for (int kk = 0; kk < 8; ++kk) {
      u32x4 v = *reinterpret_cast<const u32x4*>(
          Qb + (size_t)(qw + rt * 16 + c) * DD + kk * 32 + g * 8);
      a[rt][kk] = __builtin_bit_cast(bf16x8, v);
    }
  asm volatile("s_waitcnt vmcnt(0)" ::: "memory");

  // hoisted per-lane ds_read bases (even/odd kk parity; R7 derivation)
  const int c2 = (c >> 2) & 1;
  const int lbase = c * 512 + ((g ^ (c & 3)) << 4);
  const int base_e = lbase + c2 * 64;
  const int base_o = lbase - c2 * 64;

  float m[2][4], s[2][4];
#pragma unroll
  for (int rt = 0; rt < 2; ++rt)
#pragma unroll
    for (int r = 0; r < 4; ++r) { m[rt][r] = -3.4e38f; s[rt][r] = 0.f; }

  f32x4 acc[2][4];

  // issue 2 of this wave's 8 gload_lds for tile t (piece p = 0..3)
#define STAGE2(buf, t, p)                                                      \
  do {                                                                         \
    const char* kbase_ = (const char*)(Kb + (size_t)(j0 + (t) * KBLK) * DD);   \
    _Pragma("unroll") for (int i_ = (p) * 2; i_ < (p) * 2 + 2; ++i_) {         \
      int L_ = (w * 8 + i_) * 64 + lane;                                       \
      int row_ = L_ >> 5, ch_ = L_ & 31;                                       \
      const char* src_ = kbase_ + row_ * 512 + ((ch_ ^ (row_ & 7)) * 16);      \
      char* dst_ = &smem[buf][L_ * 16];                                        \
      __builtin_amdgcn_global_load_lds((gptr_t)src_, (lptr_t)dst_, 16, 0, 0);  \
    }                                                                          \
  } while (0)

  // 8 B-frag ds_reads for quadrant jt (even kk from base_e, odd from base_o)
#define DSREAD_Q(buf, jt, bq)                                                  \
  do {                                                                         \
    const char* se_ = &smem[buf][0] + base_e + (jt) * 8192;                    \
    const char* so_ = &smem[buf][0] + base_o + (jt) * 8192;                    \
    bq[0] = *reinterpret_cast<const bf16x8*>(se_ + 0 * 64);                    \
    bq[1] = *reinterpret_cast<const bf16x8*>(so_ + 1 * 64);                    \
    bq[2] = *reinterpret_cast<const bf16x8*>(se_ + 2 * 64);                    \
    bq[3] = *reinterpret_cast<const bf16x8*>(so_ + 3 * 64);                    \
    bq[4] = *reinterpret_cast<const bf16x8*>(se_ + 4 * 64);                    \
    bq[5] = *reinterpret_cast<const bf16x8*>(so_ + 5 * 64);                    \
    bq[6] = *reinterpret_cast<const bf16x8*>(se_ + 6 * 64);                    \
    bq[7] = *reinterpret_cast<const bf16x8*>(so_ + 7 * 64);                    \
  } while (0)

#define MFMA_Q(jt, bq)                                                         \
  do {                                                                         \
    __builtin_amdgcn_s_setprio(1);                                             \
    _Pragma("unroll") for (int kk_ = 0; kk_ < 8; ++kk_) {                      \
      acc[0][jt] = __builtin_amdgcn_mfma_f32_16x16x32_bf16(a[0][kk_], bq[kk_], acc[0][jt], 0, 0, 0); \
      acc[1][jt] = __builtin_amdgcn_mfma_f32_16x16x32_bf16(a[1][kk_], bq[kk_], acc[1][jt], 0, 0, 0); \
    }                                                                          \
    __builtin_amdgcn_s_setprio(0);                                             \
  } while (0)

  // prologue: all 8 gloads for tile 0 (consumed by tile 0 phase 0's vmcnt)
  STAGE2(0, 0, 0);
  STAGE2(0, 0, 1);
  STAGE2(0, 0, 2);
  STAGE2(0, 0, 3);

#pragma unroll 1
  for (int t = 0; t < NT; ++t) {
    const int cur = t & 1;
    const bool pf = (t + 1 < NT);

#pragma unroll
    for (int rt = 0; rt < 2; ++rt)
#pragma unroll
      for (int jt = 0; jt < 4; ++jt) acc[rt][jt] = (f32x4){0.f, 0.f, 0.f, 0.f};

    // ---- phase 0: stage-issue, COUNTED vmcnt, then quad 0
    {
      if (pf) {
        STAGE2(cur ^ 1, t + 1, 0);                          // 2 new in flight
        asm volatile("s_waitcnt vmcnt(2)" ::: "memory");    // tile t's 8 landed
      } else {
        asm volatile("s_waitcnt vmcnt(0)" ::: "memory");
      }
      __builtin_amdgcn_s_barrier();
      bf16x8 bq[8];
      DSREAD_Q(cur, 0, bq);
      asm volatile("s_waitcnt lgkmcnt(0)" ::: "memory");
      MFMA_Q(0, bq);
      __builtin_amdgcn_s_barrier();
    }
    // ---- phases 1..3: ds_read + stage before barrier, MFMA after
#pragma unroll
    for (int jt = 1; jt < 4; ++jt) {
      bf16x8 bq[8];
      DSREAD_Q(cur, jt, bq);
      if (pf) STAGE2(cur ^ 1, t + 1, jt);
      __builtin_amdgcn_s_barrier();
      asm volatile("s_waitcnt lgkmcnt(0)" ::: "memory");
      MFMA_Q(jt, bq);
      __builtin_amdgcn_s_barrier();
    }

    // ---- fold this tile (register-only, grouped 4-score chains)
#pragma unroll
    for (int rt = 0; rt < 2; ++rt)
#pragma unroll
      for (int r = 0; r < 4; ++r) {
        float v0 = acc[rt][0][r], v1 = acc[rt][1][r];
        float v2 = acc[rt][2][r], v3 = acc[rt][3][r];
        float tm = fmaxf(fmaxf(v0, v1), fmaxf(v2, v3));
        float mo = m[rt][r];
        float mn = fmaxf(mo, tm);
        float sc = fexp2(mo - mn);
        s[rt][r] = s[rt][r] * sc +
                   (fexp2(v0 - mn) + fexp2(v1 - mn) + fexp2(v2 - mn) + fexp2(v3 - mn));
        m[rt][r] = mn;
      }
  }
#undef STAGE2
#undef DSREAD_Q
#undef MFMA_Q

  // merge the 16 lanes of each group (each held a 4-col-stride slice)
#pragma unroll
  for (int rt = 0; rt < 2; ++rt)
#pragma unroll
    for (int r = 0; r < 4; ++r) {
      float M = m[rt][r], S = s[rt][r];
#pragma unroll
      for (int off = 1; off < 16; off <<= 1) {
        float Mo = __shfl_xor(M, off);
        float So = __shfl_xor(S, off);
        float Mn = fmaxf(M, Mo);
        S = S * fexp2(M - Mn) + So * fexp2(Mo - Mn);
        M = Mn;
      }
      if (c == 0) {
        int row = qw + rt * 16 + g * 4 + r;
        pm[blockIdx.y * NQ + row] = M;
        ps[blockIdx.y * NQ + row] = S;
      }
    }
}

// ---------------------------------------------------------------------------
// Kernel 3: per-row lse (base-2 partials -> natural), block-sum -> part[64]
// ---------------------------------------------------------------------------
__global__ __launch_bounds__(128) void finalize1_kernel(
    const float* __restrict__ pm, const float* __restrict__ ps,
    float* __restrict__ part) {
  const int tid = threadIdx.x;
  const int row = blockIdx.x * 128 + tid;
  float M = -3.4e38f;
#pragma unroll
  for (int k = 0; k < NSPLIT; ++k) M = fmaxf(M, pm[k * NQ + row]);
  float S = 0.f;
#pragma unroll
  for (int k = 0; k < NSPLIT; ++k) S += ps[k * NQ + row] * fexp2(pm[k * NQ + row] - M);
  float v = LN2 * (M + flog2(S));

  __shared__ float red[128];
  red[tid] = v;
  __syncthreads();
#pragma unroll
  for (int st = 64; st > 0; st >>= 1) {
    if (tid < st) red[tid] += red[tid + st];
    __syncthreads();
  }
  if (tid == 0) part[blockIdx.x] = red[0];
}

// ---------------------------------------------------------------------------
// Kernel 4: sum 64 partials, negate.
// ---------------------------------------------------------------------------
__global__ __launch_bounds__(64) void finalize2_kernel(
    const float* __restrict__ part, float* __restrict__ out) {
  const int lane = threadIdx.x;
  float v = part[lane];
#pragma unroll
  for (int off = 1; off < 64; off <<= 1) v += __shfl_xor(v, off);
  if (lane == 0) out[0] = -v;
}

// ---------------------------------------------------------------------------
extern "C" void kernel_launch(void* const* d_in, const int* in_sizes, int n_in,
                              void* d_out, int out_size, void* d_ws, size_t ws_size,
                              hipStream_t stream) {
  const float* xq = (const float*)d_in[0];
  const float* xk = (const float*)d_in[1];
  const float* Wq = (const float*)d_in[2];
  const float* Wk = (const float*)d_in[3];

  char* ws = (char*)d_ws;
  // ws: Qb 4MB | Kb 4MB | pm 256KB | ps 256KB | part 256B
  ushort_t* Qb = (ushort_t*)(ws);
  ushort_t* Kb = (ushort_t*)(ws + (size_t)NQ * DD * 2);
  float* pm = (float*)(ws + (size_t)(NQ + NK) * DD * 2);
  float* ps = pm + (size_t)NSPLIT * NQ;
  float* part = ps + (size_t)NSPLIT * NQ;

  hipLaunchKernelGGL(proj_kernel, dim3(128, 2, 4), dim3(256), 0, stream,
                     xq, xk, Wq, Wk, Qb, Kb);
  hipLaunchKernelGGL(scores_lse_kernel, dim3(NQ / 128, NSPLIT), dim3(256), 0, stream,
                     Qb, Kb, pm, ps);
  hipLaunchKernelGGL(finalize1_kernel, dim3(64), dim3(128), 0, stream, pm, ps, part);
  hipLaunchKernelGGL(finalize2_kernel, dim3(1), dim3(64), 0, stream, part, (float*)d_out);
}